// Round 4
// baseline (527.463 us; speedup 1.0000x reference)
//
#include <hip/hip_runtime.h>
#include <hip/hip_bf16.h>

// Problem constants (S=2048, B=2, E=2048, H=32, D=64)
#define S_LEN 2048
#define BATCH 2
#define EMB   2048
#define NH    32
#define HD    64
#define M_ROWS (S_LEN * BATCH)   // 4096
#define QKV_N  (3 * EMB)         // 6144

typedef short bf16x8 __attribute__((ext_vector_type(8)));
typedef float f32x4  __attribute__((ext_vector_type(4)));

__device__ __forceinline__ unsigned short f2bf(float f) {
  unsigned int u = __float_as_uint(f);
  u += 0x7fffu + ((u >> 16) & 1u);       // round-to-nearest-even
  return (unsigned short)(u >> 16);
}
__device__ __forceinline__ float bf2f(unsigned short h) {
  return __uint_as_float(((unsigned int)h) << 16);
}
__device__ __forceinline__ void async_copy16(const void* g, void* lds) {
  __builtin_amdgcn_global_load_lds(
      (const __attribute__((address_space(1))) void*)g,
      (__attribute__((address_space(3))) void*)lds, 16, 0, 0);
}

#if __has_builtin(__builtin_amdgcn_exp2f)
#define EXP2F(x) __builtin_amdgcn_exp2f(x)
#else
#define EXP2F(x) __expf((x) * 0.6931471805599453f)
#endif

// ---------------- prep kernels ----------------

__global__ __launch_bounds__(256) void cast_to_bf16(
    const float* __restrict__ in, unsigned short* __restrict__ out, int n4) {
  int i = blockIdx.x * 256 + threadIdx.x;
  if (i >= n4) return;
  float4 v = reinterpret_cast<const float4*>(in)[i];
  ushort4 o;
  o.x = f2bf(v.x); o.y = f2bf(v.y); o.z = f2bf(v.z); o.w = f2bf(v.w);
  reinterpret_cast<ushort4*>(out)[i] = o;
}

// in [R][C] f32 -> out [C][R] bf16
__global__ __launch_bounds__(256) void transpose_cast(
    const float* __restrict__ in, unsigned short* __restrict__ out, int R, int C) {
  __shared__ float tile[32][33];
  const int bc = blockIdx.x * 32, br = blockIdx.y * 32;
  const int tx = threadIdx.x & 31, ty = threadIdx.x >> 5;   // ty 0..7
  #pragma unroll
  for (int rr = ty; rr < 32; rr += 8)
    tile[rr][tx] = in[(size_t)(br + rr) * C + bc + tx];
  __syncthreads();
  #pragma unroll
  for (int rr = ty; rr < 32; rr += 8)
    out[(size_t)(bc + rr) * R + br + tx] = f2bf(tile[tx][rr]);
}

// ---------------- QKV GEMM, BK=64 swizzled LDS, fused bias+RoPE+scatter ----------------
// LDS layout: [k/8][128][8] so global_load_lds stays lane-affine (no padding)
// while ds_read_b128 fragment reads hit the minimal 8-phase bank pattern.

__global__ __launch_bounds__(256) void gemm_qkv(
    const unsigned short* __restrict__ A,
    const unsigned short* __restrict__ Wt,
    const float* __restrict__ bias,
    unsigned short* __restrict__ Qo,
    unsigned short* __restrict__ Ko,
    unsigned short* __restrict__ Vo) {
  __shared__ __align__(16) unsigned short As[128 * 64];
  __shared__ __align__(16) unsigned short Bs[128 * 64];
  const int tid = threadIdx.x;
  const int n0 = blockIdx.x * 128;
  const int m0 = blockIdx.y * 128;
  const int wave = tid >> 6, lane = tid & 63;
  const int wm = (wave >> 1) * 64, wn = (wave & 1) * 64;
  const int lm = lane & 15, lq = lane >> 4;
  const int K = 2048;

  // staging: chunk c = tid + 256*rep -> ks8 = c>>7, row = c&127; LDS off = c*16B
  const int srow = tid & 127;
  const int sk0  = (tid >> 7) * 8;                 // 0 or 8 (elements)
  const unsigned short* Ab = A  + (size_t)(m0 + srow) * K + sk0;
  const unsigned short* Bb = Wt + (size_t)(n0 + srow) * K + sk0;

  f32x4 acc[4][4] = {};

  for (int k0 = 0; k0 < K; k0 += 64) {
    #pragma unroll
    for (int rep = 0; rep < 4; rep++) {
      async_copy16(Ab + k0 + rep * 16, As + (size_t)(tid + 256 * rep) * 8);
      async_copy16(Bb + k0 + rep * 16, Bs + (size_t)(tid + 256 * rep) * 8);
    }
    __syncthreads();
    #pragma unroll
    for (int ks = 0; ks < 2; ks++) {
      bf16x8 a[4], b[4];
      #pragma unroll
      for (int i = 0; i < 4; i++)
        a[i] = *reinterpret_cast<const bf16x8*>(
            As + (size_t)((ks*4 + lq) * 128 + wm + i*16 + lm) * 8);
      #pragma unroll
      for (int j = 0; j < 4; j++)
        b[j] = *reinterpret_cast<const bf16x8*>(
            Bs + (size_t)((ks*4 + lq) * 128 + wn + j*16 + lm) * 8);
      #pragma unroll
      for (int i = 0; i < 4; i++)
        #pragma unroll
        for (int j = 0; j < 4; j++)
          acc[i][j] = __builtin_amdgcn_mfma_f32_16x16x32_bf16(a[i], b[j], acc[i][j], 0, 0, 0);
    }
    __syncthreads();
  }

  // epilogue: bias (+RoPE for Q/K) + bf16 + scatter into [B,H,S,D]
  const int which = n0 >> 11;   // 0=q 1=k 2=v, uniform per block
  unsigned short* dst = (which == 0) ? Qo : (which == 1) ? Ko : Vo;
  float bv[4];
  #pragma unroll
  for (int j = 0; j < 4; j++) bv[j] = bias[n0 + wn + j*16 + lm];

  if (which < 2) {
    // RoPE pairs (d, d+32) = (acc[i][j], acc[i][j+2]) for j=0,1 (d = j*16+lm)
    #pragma unroll
    for (int j = 0; j < 2; j++) {
      const int n = n0 + wn + j*16 + lm;
      const int e = n & (EMB - 1), h = e >> 6, d = e & 63;   // d = j*16+lm < 32
      const float invf = EXP2F((float)d * -0.4152410118609203f);  // 10000^(-d/32)
      #pragma unroll
      for (int i = 0; i < 4; i++) {
        #pragma unroll
        for (int r = 0; r < 4; r++) {
          const int m = m0 + wm + i*16 + lq*4 + r;
          const int s = m >> 1, b = m & 1;
          const float v1 = acc[i][j][r]   + bv[j];
          const float v2 = acc[i][j+2][r] + bv[j+2];
          float sn, cs;
          __sincosf((float)s * invf, &sn, &cs);
          const size_t base = (((size_t)b * NH + h) * S_LEN + s) * HD + d;
          dst[base]      = f2bf(v1 * cs - v2 * sn);
          dst[base + 32] = f2bf(v2 * cs + v1 * sn);
        }
      }
    }
  } else {
    #pragma unroll
    for (int j = 0; j < 4; j++) {
      const int n = n0 + wn + j*16 + lm;
      const int e = n & (EMB - 1), h = e >> 6, d = e & 63;
      #pragma unroll
      for (int i = 0; i < 4; i++) {
        #pragma unroll
        for (int r = 0; r < 4; r++) {
          const int m = m0 + wm + i*16 + lq*4 + r;
          const int s = m >> 1, b = m & 1;
          dst[(((size_t)b * NH + h) * S_LEN + s) * HD + d] = f2bf(acc[i][j][r] + bv[j]);
        }
      }
    }
  }
}

// ---------------- V [B,H,S,D] -> VT [B,H,D,S] ----------------

__global__ __launch_bounds__(256) void transpose_v(
    const unsigned short* __restrict__ V, unsigned short* __restrict__ VT) {
  __shared__ unsigned short t[64][65];
  const int bh = blockIdx.y;
  const int s0 = blockIdx.x * 64;
  const int tx = threadIdx.x & 63, ty = threadIdx.x >> 6;  // ty 0..3
  const unsigned short* src = V + ((size_t)bh * S_LEN + s0) * HD;
  #pragma unroll
  for (int r = ty; r < 64; r += 4)
    t[r][tx] = src[(size_t)r * HD + tx];
  __syncthreads();
  unsigned short* dst = VT + (size_t)bh * HD * S_LEN + s0;
  #pragma unroll
  for (int r = ty; r < 64; r += 4)
    dst[(size_t)r * S_LEN + tx] = t[tx][r];
}

// ---------------- Flash attention (causal), bf16 MFMA, fixed-max softmax ----------------
// Block = (head, 128 q-rows); 4 waves x 32 rows. K/V tiles staged in LDS via
// global_load_lds, shared by all 4 waves. Causal balance: block p runs strips
// p and 15-p. Fixed-max softmax: per-lane l partials, no K-loop shuffles.

__device__ __forceinline__ void attn_qblock(
    const char* __restrict__ Qb8,
    const char* __restrict__ Kb8,
    const char* __restrict__ Vb8,
    unsigned short* __restrict__ ctx,
    char* __restrict__ KsB,            // [2][64][32] bf16 halves
    char* __restrict__ VsB,            // [2][64][32]
    unsigned short* __restrict__ Pw,   // per-wave [32][72]
    int q0, int b, int h, int tid, int wave, int lm, int lq) {
  const float C = 0.18033688011112042f;   // (1/8) * log2(e)
  const int r0 = q0 + wave * 32;
  const int nt = (q0 >> 6) + 2;
  const int srow_c = r0 + lq * 4;         // this lane's C-layout row base (i=0)

  // staging indices: thread -> (row, 16B chunk)
  const int srw = tid >> 2, sc16 = (tid & 3) * 16;

  // Q fragments (A-layout): rows r0+i*16+lm, k = ks*32 + lq*8
  bf16x8 qf[2][2];
  #pragma unroll
  for (int i = 0; i < 2; i++)
    #pragma unroll
    for (int ks = 0; ks < 2; ks++)
      qf[i][ks] = *reinterpret_cast<const bf16x8*>(
          Qb8 + (size_t)(r0 + i*16 + lm) * 128 + ks*64 + lq*16);

  f32x4 O[2][4] = {};
  float l[2][4] = {};

  for (int t = 0; t < nt; t++) {
    const int t0 = t * 64;
    // ---- stage K tile (rows t0..t0+63) and V^T tile (cols t0..t0+63) ----
    async_copy16(Kb8 + (size_t)(t0 + srw) * 128      + sc16, KsB        + tid*16);
    async_copy16(Kb8 + (size_t)(t0 + srw) * 128 + 64 + sc16, KsB + 4096 + tid*16);
    async_copy16(Vb8 + (size_t)srw * 4096 + t0*2      + sc16, VsB        + tid*16);
    async_copy16(Vb8 + (size_t)srw * 4096 + t0*2 + 64 + sc16, VsB + 4096 + tid*16);
    __syncthreads();

    if (t0 <= r0 + 31) {
      const bool clean = (t0 + 63 <= r0);
      const int jmax  = clean ? 4 : ((r0 == t0) ? 2 : 4);
      const int kslim = clean ? 2 : ((r0 == t0) ? 1 : 2);

      // S = Q K^T from LDS halves
      f32x4 sc[2][4] = {};
      #pragma unroll
      for (int ks = 0; ks < 2; ks++) {
        bf16x8 kf[4];
        #pragma unroll
        for (int j = 0; j < 4; j++)
          if (j < jmax)
            kf[j] = *reinterpret_cast<const bf16x8*>(
                KsB + ks*4096 + (j*16 + lm)*64 + lq*16);
        #pragma unroll
        for (int i = 0; i < 2; i++)
          #pragma unroll
          for (int j = 0; j < 4; j++)
            if (j < jmax)
              sc[i][j] = __builtin_amdgcn_mfma_f32_16x16x32_bf16(qf[i][ks], kf[j], sc[i][j], 0, 0, 0);
      }

      // exp (fixed max), accumulate per-lane l, write P
      if (clean) {
        #pragma unroll
        for (int i = 0; i < 2; i++)
          #pragma unroll
          for (int j = 0; j < 4; j++)
            #pragma unroll
            for (int r = 0; r < 4; r++) {
              const float p = EXP2F(sc[i][j][r] * C);
              l[i][r] += p;
              Pw[(i*16 + lq*4 + r) * 72 + j*16 + lm] = f2bf(p);
            }
      } else {
        #pragma unroll
        for (int i = 0; i < 2; i++)
          #pragma unroll
          for (int j = 0; j < 4; j++)
            if (j < jmax)
              #pragma unroll
              for (int r = 0; r < 4; r++) {
                const int srow = srow_c + i*16 + r;
                const int tcol = t0 + j*16 + lm;
                const float p = (tcol <= srow) ? EXP2F(sc[i][j][r] * C) : 0.0f;
                l[i][r] += p;
                Pw[(i*16 + lq*4 + r) * 72 + j*16 + lm] = f2bf(p);
              }
      }

      // O += P V
      #pragma unroll
      for (int ks = 0; ks < 2; ks++) {
        if (ks < kslim) {
          bf16x8 pf[2], vf[4];
          #pragma unroll
          for (int i = 0; i < 2; i++)
            pf[i] = *reinterpret_cast<const bf16x8*>(Pw + (i*16 + lm)*72 + ks*32 + lq*8);
          #pragma unroll
          for (int j = 0; j < 4; j++)
            vf[j] = *reinterpret_cast<const bf16x8*>(
                VsB + ks*4096 + (j*16 + lm)*64 + lq*16);
          #pragma unroll
          for (int i = 0; i < 2; i++)
            #pragma unroll
            for (int j = 0; j < 4; j++)
              O[i][j] = __builtin_amdgcn_mfma_f32_16x16x32_bf16(pf[i], vf[j], O[i][j], 0, 0, 0);
        }
      }
    }
    __syncthreads();
  }

  // epilogue: reduce l across 16-lane column groups, scale, store ctx [S,B,E]
  #pragma unroll
  for (int i = 0; i < 2; i++) {
    #pragma unroll
    for (int r = 0; r < 4; r++) {
      float s = l[i][r];
      s += __shfl_xor(s, 1, 64);
      s += __shfl_xor(s, 2, 64);
      s += __shfl_xor(s, 4, 64);
      s += __shfl_xor(s, 8, 64);
      const float inv = 1.0f / s;
      const int srow = srow_c + i*16 + r;
      #pragma unroll
      for (int j = 0; j < 4; j++) {
        const int d = j*16 + lm;
        ctx[((size_t)srow * BATCH + b) * EMB + h*HD + d] = f2bf(O[i][j][r] * inv);
      }
    }
  }
}

__global__ __launch_bounds__(256) void attn_kernel(
    const unsigned short* __restrict__ Q,
    const unsigned short* __restrict__ K,
    const unsigned short* __restrict__ VT,
    unsigned short* __restrict__ ctx) {
  const int bh = blockIdx.x;               // b*32+h
  const int p  = blockIdx.y;               // 0..7 strip pair
  const int tid = threadIdx.x;
  const int wave = tid >> 6, lane = tid & 63;
  const int lm = lane & 15, lq = lane >> 4;
  const int b = bh >> 5, h = bh & 31;
  const char* Qb8 = (const char*)(Q  + (size_t)bh * S_LEN * HD);
  const char* Kb8 = (const char*)(K  + (size_t)bh * S_LEN * HD);
  const char* Vb8 = (const char*)(VT + (size_t)bh * HD * S_LEN);

  __shared__ __align__(16) unsigned short Ks[2][64][32];
  __shared__ __align__(16) unsigned short Vs[2][64][32];
  __shared__ __align__(16) unsigned short Pbuf[4][32][72];
  char* KsB = (char*)&Ks[0][0][0];
  char* VsB = (char*)&Vs[0][0][0];
  unsigned short* Pw = &Pbuf[wave][0][0];

  // paired strips: p (light) and 15-p (heavy) -> uniform 34 tiles/block
  attn_qblock(Qb8, Kb8, Vb8, ctx, KsB, VsB, Pw, p * 128,        b, h, tid, wave, lm, lq);
  attn_qblock(Qb8, Kb8, Vb8, ctx, KsB, VsB, Pw, (15 - p) * 128, b, h, tid, wave, lm, lq);
}

// ---------------- Output GEMM: ctx[4096,2048]bf16 x outWt[2048,2048]bf16 + bias -> f32 ----------------

__global__ __launch_bounds__(256) void gemm_out(
    const unsigned short* __restrict__ A,
    const unsigned short* __restrict__ Wt,
    const float* __restrict__ bias,
    float* __restrict__ out) {
  __shared__ __align__(16) unsigned short As[128 * 64];
  __shared__ __align__(16) unsigned short Bs[128 * 64];
  const int tid = threadIdx.x;
  const int n0 = blockIdx.x * 128;
  const int m0 = blockIdx.y * 128;
  const int wave = tid >> 6, lane = tid & 63;
  const int wm = (wave >> 1) * 64, wn = (wave & 1) * 64;
  const int lm = lane & 15, lq = lane >> 4;
  const int K = 2048;

  const int srow = tid & 127;
  const int sk0  = (tid >> 7) * 8;
  const unsigned short* Ab = A  + (size_t)(m0 + srow) * K + sk0;
  const unsigned short* Bb = Wt + (size_t)(n0 + srow) * K + sk0;

  f32x4 acc[4][4] = {};

  for (int k0 = 0; k0 < K; k0 += 64) {
    #pragma unroll
    for (int rep = 0; rep < 4; rep++) {
      async_copy16(Ab + k0 + rep * 16, As + (size_t)(tid + 256 * rep) * 8);
      async_copy16(Bb + k0 + rep * 16, Bs + (size_t)(tid + 256 * rep) * 8);
    }
    __syncthreads();
    #pragma unroll
    for (int ks = 0; ks < 2; ks++) {
      bf16x8 a[4], b[4];
      #pragma unroll
      for (int i = 0; i < 4; i++)
        a[i] = *reinterpret_cast<const bf16x8*>(
            As + (size_t)((ks*4 + lq) * 128 + wm + i*16 + lm) * 8);
      #pragma unroll
      for (int j = 0; j < 4; j++)
        b[j] = *reinterpret_cast<const bf16x8*>(
            Bs + (size_t)((ks*4 + lq) * 128 + wn + j*16 + lm) * 8);
      #pragma unroll
      for (int i = 0; i < 4; i++)
        #pragma unroll
        for (int j = 0; j < 4; j++)
          acc[i][j] = __builtin_amdgcn_mfma_f32_16x16x32_bf16(a[i], b[j], acc[i][j], 0, 0, 0);
    }
    __syncthreads();
  }

  #pragma unroll
  for (int j = 0; j < 4; j++) {
    const int n = n0 + wn + j*16 + lm;
    const float bv = bias[n];
    #pragma unroll
    for (int i = 0; i < 4; i++) {
      #pragma unroll
      for (int r = 0; r < 4; r++) {
        const int m = m0 + wm + i*16 + lq*4 + r;
        out[(size_t)m * EMB + n] = acc[i][j][r] + bv;
      }
    }
  }
}

// ---------------- host launcher ----------------

extern "C" void kernel_launch(void* const* d_in, const int* in_sizes, int n_in,
                              void* d_out, int out_size, void* d_ws, size_t ws_size,
                              hipStream_t stream) {
  const float* hidden = (const float*)d_in[0];
  const float* qkv_w  = (const float*)d_in[1];
  const float* qkv_b  = (const float*)d_in[2];
  const float* out_w  = (const float*)d_in[3];
  const float* out_b  = (const float*)d_in[4];
  float* out = (float*)d_out;

  unsigned short* ws = (unsigned short*)d_ws;
  unsigned short* hbf   = ws;                                  // 4096*2048
  unsigned short* qkvwT = hbf   + (size_t)M_ROWS * EMB;        // 6144*2048
  unsigned short* outwT = qkvwT + (size_t)QKV_N * EMB;         // 2048*2048
  unsigned short* Qb    = outwT + (size_t)EMB * EMB;           // 64*2048*64 each
  unsigned short* Kb    = Qb    + (size_t)64 * S_LEN * HD;
  unsigned short* Vb    = Kb    + (size_t)64 * S_LEN * HD;
  unsigned short* VTb   = Vb    + (size_t)64 * S_LEN * HD;
  unsigned short* ctx   = VTb   + (size_t)64 * S_LEN * HD;     // 4096*2048

  // 1. casts / transposes
  cast_to_bf16<<<(M_ROWS * EMB / 4) / 256, 256, 0, stream>>>(hidden, hbf, M_ROWS * EMB / 4);
  transpose_cast<<<dim3(QKV_N / 32, EMB / 32), 256, 0, stream>>>(qkv_w, qkvwT, EMB, QKV_N);
  transpose_cast<<<dim3(EMB / 32, EMB / 32), 256, 0, stream>>>(out_w, outwT, EMB, EMB);

  // 2. fused QKV projection + bias + RoPE + scatter
  gemm_qkv<<<dim3(QKV_N / 128, M_ROWS / 128), 256, 0, stream>>>(hbf, qkvwT, qkv_b, Qb, Kb, Vb);

  // 3. V transpose
  transpose_v<<<dim3(S_LEN / 64, 64), 256, 0, stream>>>(Vb, VTb);

  // 4. causal flash attention (LDS-staged K/V, paired strips)
  attn_kernel<<<dim3(64, 8), 256, 0, stream>>>(Qb, Kb, VTb, ctx);

  // 5. output projection
  gemm_out<<<dim3(EMB / 128, M_ROWS / 128), 256, 0, stream>>>(ctx, outwT, out_b, out);
}

// Round 5
// 380.611 us; speedup vs baseline: 1.3858x; 1.3858x over previous
//
#include <hip/hip_runtime.h>
#include <hip/hip_bf16.h>

// Problem constants (S=2048, B=2, E=2048, H=32, D=64)
#define S_LEN 2048
#define BATCH 2
#define EMB   2048
#define NH    32
#define HD    64
#define M_ROWS (S_LEN * BATCH)   // 4096
#define QKV_N  (3 * EMB)         // 6144

typedef short bf16x8 __attribute__((ext_vector_type(8)));
typedef float f32x4  __attribute__((ext_vector_type(4)));

__device__ __forceinline__ unsigned short f2bf(float f) {
  unsigned int u = __float_as_uint(f);
  u += 0x7fffu + ((u >> 16) & 1u);       // round-to-nearest-even
  return (unsigned short)(u >> 16);
}
__device__ __forceinline__ float bf2f(unsigned short h) {
  return __uint_as_float(((unsigned int)h) << 16);
}
__device__ __forceinline__ void async_copy16(const void* g, void* lds) {
  __builtin_amdgcn_global_load_lds(
      (const __attribute__((address_space(1))) void*)g,
      (__attribute__((address_space(3))) void*)lds, 16, 0, 0);
}

#if __has_builtin(__builtin_amdgcn_exp2f)
#define EXP2F(x) __builtin_amdgcn_exp2f(x)
#else
#define EXP2F(x) __expf((x) * 0.6931471805599453f)
#endif

// ---------------- prep kernels ----------------

__global__ __launch_bounds__(256) void cast_to_bf16(
    const float* __restrict__ in, unsigned short* __restrict__ out, int n4) {
  int i = blockIdx.x * 256 + threadIdx.x;
  if (i >= n4) return;
  float4 v = reinterpret_cast<const float4*>(in)[i];
  ushort4 o;
  o.x = f2bf(v.x); o.y = f2bf(v.y); o.z = f2bf(v.z); o.w = f2bf(v.w);
  reinterpret_cast<ushort4*>(out)[i] = o;
}

// in [R][C] f32 -> out [C][R] bf16
__global__ __launch_bounds__(256) void transpose_cast(
    const float* __restrict__ in, unsigned short* __restrict__ out, int R, int C) {
  __shared__ float tile[32][33];
  const int bc = blockIdx.x * 32, br = blockIdx.y * 32;
  const int tx = threadIdx.x & 31, ty = threadIdx.x >> 5;   // ty 0..7
  #pragma unroll
  for (int rr = ty; rr < 32; rr += 8)
    tile[rr][tx] = in[(size_t)(br + rr) * C + bc + tx];
  __syncthreads();
  #pragma unroll
  for (int rr = ty; rr < 32; rr += 8)
    out[(size_t)(bc + rr) * R + br + tx] = f2bf(tile[tx][rr]);
}

// ---------------- QKV GEMM, BK=64, XOR-swizzled LDS, fused bias+RoPE+scatter ----
// Staging is coalesced (8 lanes cover one contiguous 128B row segment); the XOR
// swizzle is applied to the GLOBAL chunk index (LDS dest of global_load_lds is
// forced lane-affine). LDS[row][p] holds global chunk p^(row&7); fragment reads
// address physical chunk (ks*4+lq)^(row&7) -> 2-way bank aliasing only (free).

__global__ __launch_bounds__(256) void gemm_qkv(
    const unsigned short* __restrict__ A,
    const unsigned short* __restrict__ Wt,
    const float* __restrict__ bias,
    unsigned short* __restrict__ Qo,
    unsigned short* __restrict__ Ko,
    unsigned short* __restrict__ Vo) {
  __shared__ __align__(16) unsigned short As[128 * 64];
  __shared__ __align__(16) unsigned short Bs[128 * 64];
  const int tid = threadIdx.x;
  const int n0 = blockIdx.x * 128;
  const int m0 = blockIdx.y * 128;
  const int wave = tid >> 6, lane = tid & 63;
  const int wm = (wave >> 1) * 64, wn = (wave & 1) * 64;
  const int lm = lane & 15, lq = lane >> 4;
  const int K = 2048;

  // staging: row = rep*32 + (tid>>3); phys chunk p = tid&7 reads global chunk p^(row&7)
  const int srow = tid >> 3;                       // 0..31
  const int gch  = (tid & 7) ^ (srow & 7);
  const unsigned short* Ab = A  + (size_t)(m0 + srow) * K + gch * 8;
  const unsigned short* Bb = Wt + (size_t)(n0 + srow) * K + gch * 8;

  f32x4 acc[4][4] = {};

  for (int k0 = 0; k0 < K; k0 += 64) {
    #pragma unroll
    for (int rep = 0; rep < 4; rep++) {
      async_copy16(Ab + (size_t)rep * 32 * K + k0, As + (size_t)(tid + 256 * rep) * 8);
      async_copy16(Bb + (size_t)rep * 32 * K + k0, Bs + (size_t)(tid + 256 * rep) * 8);
    }
    __syncthreads();
    #pragma unroll
    for (int ks = 0; ks < 2; ks++) {
      bf16x8 a[4], b[4];
      #pragma unroll
      for (int i = 0; i < 4; i++) {
        const int R = wm + i*16 + lm;
        a[i] = *reinterpret_cast<const bf16x8*>(
            As + (size_t)R * 64 + (((ks*4 + lq) ^ (R & 7)) * 8));
      }
      #pragma unroll
      for (int j = 0; j < 4; j++) {
        const int R = wn + j*16 + lm;
        b[j] = *reinterpret_cast<const bf16x8*>(
            Bs + (size_t)R * 64 + (((ks*4 + lq) ^ (R & 7)) * 8));
      }
      #pragma unroll
      for (int i = 0; i < 4; i++)
        #pragma unroll
        for (int j = 0; j < 4; j++)
          acc[i][j] = __builtin_amdgcn_mfma_f32_16x16x32_bf16(a[i], b[j], acc[i][j], 0, 0, 0);
    }
    __syncthreads();
  }

  // epilogue: bias (+RoPE for Q/K) + bf16 + scatter into [B,H,S,D]
  const int which = n0 >> 11;   // 0=q 1=k 2=v, uniform per block
  unsigned short* dst = (which == 0) ? Qo : (which == 1) ? Ko : Vo;
  float bv[4];
  #pragma unroll
  for (int j = 0; j < 4; j++) bv[j] = bias[n0 + wn + j*16 + lm];

  if (which < 2) {
    // RoPE pairs (d, d+32) = (acc[i][j], acc[i][j+2]) for j=0,1 (d = j*16+lm)
    #pragma unroll
    for (int j = 0; j < 2; j++) {
      const int n = n0 + wn + j*16 + lm;
      const int e = n & (EMB - 1), h = e >> 6, d = e & 63;   // d = j*16+lm < 32
      const float invf = EXP2F((float)d * -0.4152410118609203f);  // 10000^(-d/32)
      #pragma unroll
      for (int i = 0; i < 4; i++) {
        #pragma unroll
        for (int r = 0; r < 4; r++) {
          const int m = m0 + wm + i*16 + lq*4 + r;
          const int s = m >> 1, b = m & 1;
          const float v1 = acc[i][j][r]   + bv[j];
          const float v2 = acc[i][j+2][r] + bv[j+2];
          float sn, cs;
          __sincosf((float)s * invf, &sn, &cs);
          const size_t base = (((size_t)b * NH + h) * S_LEN + s) * HD + d;
          dst[base]      = f2bf(v1 * cs - v2 * sn);
          dst[base + 32] = f2bf(v2 * cs + v1 * sn);
        }
      }
    }
  } else {
    #pragma unroll
    for (int j = 0; j < 4; j++) {
      const int n = n0 + wn + j*16 + lm;
      const int e = n & (EMB - 1), h = e >> 6, d = e & 63;
      #pragma unroll
      for (int i = 0; i < 4; i++) {
        #pragma unroll
        for (int r = 0; r < 4; r++) {
          const int m = m0 + wm + i*16 + lq*4 + r;
          const int s = m >> 1, b = m & 1;
          dst[(((size_t)b * NH + h) * S_LEN + s) * HD + d] = f2bf(acc[i][j][r] + bv[j]);
        }
      }
    }
  }
}

// ---------------- V [B,H,S,D] -> VT [B,H,D,S] ----------------

__global__ __launch_bounds__(256) void transpose_v(
    const unsigned short* __restrict__ V, unsigned short* __restrict__ VT) {
  __shared__ unsigned short t[64][65];
  const int bh = blockIdx.y;
  const int s0 = blockIdx.x * 64;
  const int tx = threadIdx.x & 63, ty = threadIdx.x >> 6;  // ty 0..3
  const unsigned short* src = V + ((size_t)bh * S_LEN + s0) * HD;
  #pragma unroll
  for (int r = ty; r < 64; r += 4)
    t[r][tx] = src[(size_t)r * HD + tx];
  __syncthreads();
  unsigned short* dst = VT + (size_t)bh * HD * S_LEN + s0;
  #pragma unroll
  for (int r = ty; r < 64; r += 4)
    dst[(size_t)r * S_LEN + tx] = t[tx][r];
}

// ---------------- Flash attention (causal), bf16 MFMA, fixed-max softmax ----------------
// Block = (head, 128 q-rows); 4 waves x 32 rows. K/V tiles staged in LDS via
// global_load_lds, shared by all 4 waves. Causal balance: block p runs strips
// p and 15-p. Fixed-max softmax: per-lane l partials, no K-loop shuffles.

__device__ __forceinline__ void attn_qblock(
    const char* __restrict__ Qb8,
    const char* __restrict__ Kb8,
    const char* __restrict__ Vb8,
    unsigned short* __restrict__ ctx,
    char* __restrict__ KsB,            // [2][64][32] bf16 halves
    char* __restrict__ VsB,            // [2][64][32]
    unsigned short* __restrict__ Pw,   // per-wave [32][72]
    int q0, int b, int h, int tid, int wave, int lm, int lq) {
  const float C = 0.18033688011112042f;   // (1/8) * log2(e)
  const int r0 = q0 + wave * 32;
  const int nt = (q0 >> 6) + 2;
  const int srow_c = r0 + lq * 4;         // this lane's C-layout row base (i=0)

  // staging indices: thread -> (row, 16B chunk)
  const int srw = tid >> 2, sc16 = (tid & 3) * 16;

  // Q fragments (A-layout): rows r0+i*16+lm, k = ks*32 + lq*8
  bf16x8 qf[2][2];
  #pragma unroll
  for (int i = 0; i < 2; i++)
    #pragma unroll
    for (int ks = 0; ks < 2; ks++)
      qf[i][ks] = *reinterpret_cast<const bf16x8*>(
          Qb8 + (size_t)(r0 + i*16 + lm) * 128 + ks*64 + lq*16);

  f32x4 O[2][4] = {};
  float l[2][4] = {};

  for (int t = 0; t < nt; t++) {
    const int t0 = t * 64;
    // ---- stage K tile (rows t0..t0+63) and V^T tile (cols t0..t0+63) ----
    async_copy16(Kb8 + (size_t)(t0 + srw) * 128      + sc16, KsB        + tid*16);
    async_copy16(Kb8 + (size_t)(t0 + srw) * 128 + 64 + sc16, KsB + 4096 + tid*16);
    async_copy16(Vb8 + (size_t)srw * 4096 + t0*2      + sc16, VsB        + tid*16);
    async_copy16(Vb8 + (size_t)srw * 4096 + t0*2 + 64 + sc16, VsB + 4096 + tid*16);
    __syncthreads();

    if (t0 <= r0 + 31) {
      const bool clean = (t0 + 63 <= r0);
      const int jmax  = clean ? 4 : ((r0 == t0) ? 2 : 4);
      const int kslim = clean ? 2 : ((r0 == t0) ? 1 : 2);

      // S = Q K^T from LDS halves
      f32x4 sc[2][4] = {};
      #pragma unroll
      for (int ks = 0; ks < 2; ks++) {
        bf16x8 kf[4];
        #pragma unroll
        for (int j = 0; j < 4; j++)
          if (j < jmax)
            kf[j] = *reinterpret_cast<const bf16x8*>(
                KsB + ks*4096 + (j*16 + lm)*64 + lq*16);
        #pragma unroll
        for (int i = 0; i < 2; i++)
          #pragma unroll
          for (int j = 0; j < 4; j++)
            if (j < jmax)
              sc[i][j] = __builtin_amdgcn_mfma_f32_16x16x32_bf16(qf[i][ks], kf[j], sc[i][j], 0, 0, 0);
      }

      // exp (fixed max), accumulate per-lane l, write P
      if (clean) {
        #pragma unroll
        for (int i = 0; i < 2; i++)
          #pragma unroll
          for (int j = 0; j < 4; j++)
            #pragma unroll
            for (int r = 0; r < 4; r++) {
              const float p = EXP2F(sc[i][j][r] * C);
              l[i][r] += p;
              Pw[(i*16 + lq*4 + r) * 72 + j*16 + lm] = f2bf(p);
            }
      } else {
        #pragma unroll
        for (int i = 0; i < 2; i++)
          #pragma unroll
          for (int j = 0; j < 4; j++)
            if (j < jmax)
              #pragma unroll
              for (int r = 0; r < 4; r++) {
                const int srow = srow_c + i*16 + r;
                const int tcol = t0 + j*16 + lm;
                const float p = (tcol <= srow) ? EXP2F(sc[i][j][r] * C) : 0.0f;
                l[i][r] += p;
                Pw[(i*16 + lq*4 + r) * 72 + j*16 + lm] = f2bf(p);
              }
      }

      // O += P V
      #pragma unroll
      for (int ks = 0; ks < 2; ks++) {
        if (ks < kslim) {
          bf16x8 pf[2], vf[4];
          #pragma unroll
          for (int i = 0; i < 2; i++)
            pf[i] = *reinterpret_cast<const bf16x8*>(Pw + (i*16 + lm)*72 + ks*32 + lq*8);
          #pragma unroll
          for (int j = 0; j < 4; j++)
            vf[j] = *reinterpret_cast<const bf16x8*>(
                VsB + ks*4096 + (j*16 + lm)*64 + lq*16);
          #pragma unroll
          for (int i = 0; i < 2; i++)
            #pragma unroll
            for (int j = 0; j < 4; j++)
              O[i][j] = __builtin_amdgcn_mfma_f32_16x16x32_bf16(pf[i], vf[j], O[i][j], 0, 0, 0);
        }
      }
    }
    __syncthreads();
  }

  // epilogue: reduce l across 16-lane column groups, scale, store ctx [S,B,E]
  #pragma unroll
  for (int i = 0; i < 2; i++) {
    #pragma unroll
    for (int r = 0; r < 4; r++) {
      float s = l[i][r];
      s += __shfl_xor(s, 1, 64);
      s += __shfl_xor(s, 2, 64);
      s += __shfl_xor(s, 4, 64);
      s += __shfl_xor(s, 8, 64);
      const float inv = 1.0f / s;
      const int srow = srow_c + i*16 + r;
      #pragma unroll
      for (int j = 0; j < 4; j++) {
        const int d = j*16 + lm;
        ctx[((size_t)srow * BATCH + b) * EMB + h*HD + d] = f2bf(O[i][j][r] * inv);
      }
    }
  }
}

__global__ __launch_bounds__(256) void attn_kernel(
    const unsigned short* __restrict__ Q,
    const unsigned short* __restrict__ K,
    const unsigned short* __restrict__ VT,
    unsigned short* __restrict__ ctx) {
  const int bh = blockIdx.x;               // b*32+h
  const int p  = blockIdx.y;               // 0..7 strip pair
  const int tid = threadIdx.x;
  const int wave = tid >> 6, lane = tid & 63;
  const int lm = lane & 15, lq = lane >> 4;
  const int b = bh >> 5, h = bh & 31;
  const char* Qb8 = (const char*)(Q  + (size_t)bh * S_LEN * HD);
  const char* Kb8 = (const char*)(K  + (size_t)bh * S_LEN * HD);
  const char* Vb8 = (const char*)(VT + (size_t)bh * HD * S_LEN);

  __shared__ __align__(16) unsigned short Ks[2][64][32];
  __shared__ __align__(16) unsigned short Vs[2][64][32];
  __shared__ __align__(16) unsigned short Pbuf[4][32][72];
  char* KsB = (char*)&Ks[0][0][0];
  char* VsB = (char*)&Vs[0][0][0];
  unsigned short* Pw = &Pbuf[wave][0][0];

  // paired strips: p (light) and 15-p (heavy) -> uniform 34 tiles/block
  attn_qblock(Qb8, Kb8, Vb8, ctx, KsB, VsB, Pw, p * 128,        b, h, tid, wave, lm, lq);
  attn_qblock(Qb8, Kb8, Vb8, ctx, KsB, VsB, Pw, (15 - p) * 128, b, h, tid, wave, lm, lq);
}

// ---------------- Output GEMM: ctx[4096,2048]bf16 x outWt[2048,2048]bf16 + bias -> f32 ----------------
// Same BK=64 XOR-swizzled structure as gemm_qkv.

__global__ __launch_bounds__(256) void gemm_out(
    const unsigned short* __restrict__ A,
    const unsigned short* __restrict__ Wt,
    const float* __restrict__ bias,
    float* __restrict__ out) {
  __shared__ __align__(16) unsigned short As[128 * 64];
  __shared__ __align__(16) unsigned short Bs[128 * 64];
  const int tid = threadIdx.x;
  const int n0 = blockIdx.x * 128;
  const int m0 = blockIdx.y * 128;
  const int wave = tid >> 6, lane = tid & 63;
  const int wm = (wave >> 1) * 64, wn = (wave & 1) * 64;
  const int lm = lane & 15, lq = lane >> 4;
  const int K = 2048;

  const int srow = tid >> 3;
  const int gch  = (tid & 7) ^ (srow & 7);
  const unsigned short* Ab = A  + (size_t)(m0 + srow) * K + gch * 8;
  const unsigned short* Bb = Wt + (size_t)(n0 + srow) * K + gch * 8;

  f32x4 acc[4][4] = {};

  for (int k0 = 0; k0 < K; k0 += 64) {
    #pragma unroll
    for (int rep = 0; rep < 4; rep++) {
      async_copy16(Ab + (size_t)rep * 32 * K + k0, As + (size_t)(tid + 256 * rep) * 8);
      async_copy16(Bb + (size_t)rep * 32 * K + k0, Bs + (size_t)(tid + 256 * rep) * 8);
    }
    __syncthreads();
    #pragma unroll
    for (int ks = 0; ks < 2; ks++) {
      bf16x8 a[4], b[4];
      #pragma unroll
      for (int i = 0; i < 4; i++) {
        const int R = wm + i*16 + lm;
        a[i] = *reinterpret_cast<const bf16x8*>(
            As + (size_t)R * 64 + (((ks*4 + lq) ^ (R & 7)) * 8));
      }
      #pragma unroll
      for (int j = 0; j < 4; j++) {
        const int R = wn + j*16 + lm;
        b[j] = *reinterpret_cast<const bf16x8*>(
            Bs + (size_t)R * 64 + (((ks*4 + lq) ^ (R & 7)) * 8));
      }
      #pragma unroll
      for (int i = 0; i < 4; i++)
        #pragma unroll
        for (int j = 0; j < 4; j++)
          acc[i][j] = __builtin_amdgcn_mfma_f32_16x16x32_bf16(a[i], b[j], acc[i][j], 0, 0, 0);
    }
    __syncthreads();
  }

  #pragma unroll
  for (int j = 0; j < 4; j++) {
    const int n = n0 + wn + j*16 + lm;
    const float bv = bias[n];
    #pragma unroll
    for (int i = 0; i < 4; i++) {
      #pragma unroll
      for (int r = 0; r < 4; r++) {
        const int m = m0 + wm + i*16 + lq*4 + r;
        out[(size_t)m * EMB + n] = acc[i][j][r] + bv;
      }
    }
  }
}

// ---------------- host launcher ----------------

extern "C" void kernel_launch(void* const* d_in, const int* in_sizes, int n_in,
                              void* d_out, int out_size, void* d_ws, size_t ws_size,
                              hipStream_t stream) {
  const float* hidden = (const float*)d_in[0];
  const float* qkv_w  = (const float*)d_in[1];
  const float* qkv_b  = (const float*)d_in[2];
  const float* out_w  = (const float*)d_in[3];
  const float* out_b  = (const float*)d_in[4];
  float* out = (float*)d_out;

  unsigned short* ws = (unsigned short*)d_ws;
  unsigned short* hbf   = ws;                                  // 4096*2048
  unsigned short* qkvwT = hbf   + (size_t)M_ROWS * EMB;        // 6144*2048
  unsigned short* outwT = qkvwT + (size_t)QKV_N * EMB;         // 2048*2048
  unsigned short* Qb    = outwT + (size_t)EMB * EMB;           // 64*2048*64 each
  unsigned short* Kb    = Qb    + (size_t)64 * S_LEN * HD;
  unsigned short* Vb    = Kb    + (size_t)64 * S_LEN * HD;
  unsigned short* VTb   = Vb    + (size_t)64 * S_LEN * HD;
  unsigned short* ctx   = VTb   + (size_t)64 * S_LEN * HD;     // 4096*2048

  // 1. casts / transposes
  cast_to_bf16<<<(M_ROWS * EMB / 4) / 256, 256, 0, stream>>>(hidden, hbf, M_ROWS * EMB / 4);
  transpose_cast<<<dim3(QKV_N / 32, EMB / 32), 256, 0, stream>>>(qkv_w, qkvwT, EMB, QKV_N);
  transpose_cast<<<dim3(EMB / 32, EMB / 32), 256, 0, stream>>>(out_w, outwT, EMB, EMB);

  // 2. fused QKV projection + bias + RoPE + scatter
  gemm_qkv<<<dim3(QKV_N / 128, M_ROWS / 128), 256, 0, stream>>>(hbf, qkvwT, qkv_b, Qb, Kb, Vb);

  // 3. V transpose
  transpose_v<<<dim3(S_LEN / 64, 64), 256, 0, stream>>>(Vb, VTb);

  // 4. causal flash attention (LDS-staged K/V, paired strips)
  attn_kernel<<<dim3(64, 8), 256, 0, stream>>>(Qb, Kb, VTb, ctx);

  // 5. output projection
  gemm_out<<<dim3(EMB / 128, M_ROWS / 128), 256, 0, stream>>>(ctx, outwT, out_b, out);
}

// Round 6
// 368.074 us; speedup vs baseline: 1.4330x; 1.0341x over previous
//
#include <hip/hip_runtime.h>
#include <hip/hip_bf16.h>

// Problem constants (S=2048, B=2, E=2048, H=32, D=64)
#define S_LEN 2048
#define BATCH 2
#define EMB   2048
#define NH    32
#define HD    64
#define M_ROWS (S_LEN * BATCH)   // 4096
#define QKV_N  (3 * EMB)         // 6144

typedef short bf16x8 __attribute__((ext_vector_type(8)));
typedef float f32x4  __attribute__((ext_vector_type(4)));

__device__ __forceinline__ unsigned short f2bf(float f) {
  unsigned int u = __float_as_uint(f);
  u += 0x7fffu + ((u >> 16) & 1u);       // round-to-nearest-even
  return (unsigned short)(u >> 16);
}
__device__ __forceinline__ float bf2f(unsigned short h) {
  return __uint_as_float(((unsigned int)h) << 16);
}
__device__ __forceinline__ void async_copy16(const void* g, void* lds) {
  __builtin_amdgcn_global_load_lds(
      (const __attribute__((address_space(1))) void*)g,
      (__attribute__((address_space(3))) void*)lds, 16, 0, 0);
}

#if __has_builtin(__builtin_amdgcn_exp2f)
#define EXP2F(x) __builtin_amdgcn_exp2f(x)
#else
#define EXP2F(x) __expf((x) * 0.6931471805599453f)
#endif

// ---------------- prep kernels ----------------

__global__ __launch_bounds__(256) void cast_to_bf16(
    const float* __restrict__ in, unsigned short* __restrict__ out, int n4) {
  int i = blockIdx.x * 256 + threadIdx.x;
  if (i >= n4) return;
  float4 v = reinterpret_cast<const float4*>(in)[i];
  ushort4 o;
  o.x = f2bf(v.x); o.y = f2bf(v.y); o.z = f2bf(v.z); o.w = f2bf(v.w);
  reinterpret_cast<ushort4*>(out)[i] = o;
}

// in [R][C] f32 -> out [C][R] bf16
__global__ __launch_bounds__(256) void transpose_cast(
    const float* __restrict__ in, unsigned short* __restrict__ out, int R, int C) {
  __shared__ float tile[32][33];
  const int bc = blockIdx.x * 32, br = blockIdx.y * 32;
  const int tx = threadIdx.x & 31, ty = threadIdx.x >> 5;   // ty 0..7
  #pragma unroll
  for (int rr = ty; rr < 32; rr += 8)
    tile[rr][tx] = in[(size_t)(br + rr) * C + bc + tx];
  __syncthreads();
  #pragma unroll
  for (int rr = ty; rr < 32; rr += 8)
    out[(size_t)(bc + rr) * R + br + tx] = f2bf(tile[tx][rr]);
}

// ---------------- QKV GEMM, BK=64, XOR-swizzled LDS, fused bias+RoPE+scatter ----
// Staging is coalesced (8 lanes cover one contiguous 128B row segment); the XOR
// swizzle is applied to the GLOBAL chunk index (LDS dest of global_load_lds is
// forced lane-affine). LDS[row][p] holds global chunk p^(row&7); fragment reads
// address physical chunk (ks*4+lq)^(row&7) -> 2-way bank aliasing only (free).

__global__ __launch_bounds__(256) void gemm_qkv(
    const unsigned short* __restrict__ A,
    const unsigned short* __restrict__ Wt,
    const float* __restrict__ bias,
    unsigned short* __restrict__ Qo,
    unsigned short* __restrict__ Ko,
    unsigned short* __restrict__ Vo) {
  __shared__ __align__(16) unsigned short As[128 * 64];
  __shared__ __align__(16) unsigned short Bs[128 * 64];
  const int tid = threadIdx.x;
  const int n0 = blockIdx.x * 128;
  const int m0 = blockIdx.y * 128;
  const int wave = tid >> 6, lane = tid & 63;
  const int wm = (wave >> 1) * 64, wn = (wave & 1) * 64;
  const int lm = lane & 15, lq = lane >> 4;
  const int K = 2048;

  // staging: row = rep*32 + (tid>>3); phys chunk p = tid&7 reads global chunk p^(row&7)
  const int srow = tid >> 3;                       // 0..31
  const int gch  = (tid & 7) ^ (srow & 7);
  const unsigned short* Ab = A  + (size_t)(m0 + srow) * K + gch * 8;
  const unsigned short* Bb = Wt + (size_t)(n0 + srow) * K + gch * 8;

  f32x4 acc[4][4] = {};

  for (int k0 = 0; k0 < K; k0 += 64) {
    #pragma unroll
    for (int rep = 0; rep < 4; rep++) {
      async_copy16(Ab + (size_t)rep * 32 * K + k0, As + (size_t)(tid + 256 * rep) * 8);
      async_copy16(Bb + (size_t)rep * 32 * K + k0, Bs + (size_t)(tid + 256 * rep) * 8);
    }
    __syncthreads();
    #pragma unroll
    for (int ks = 0; ks < 2; ks++) {
      bf16x8 a[4], b[4];
      #pragma unroll
      for (int i = 0; i < 4; i++) {
        const int R = wm + i*16 + lm;
        a[i] = *reinterpret_cast<const bf16x8*>(
            As + (size_t)R * 64 + (((ks*4 + lq) ^ (R & 7)) * 8));
      }
      #pragma unroll
      for (int j = 0; j < 4; j++) {
        const int R = wn + j*16 + lm;
        b[j] = *reinterpret_cast<const bf16x8*>(
            Bs + (size_t)R * 64 + (((ks*4 + lq) ^ (R & 7)) * 8));
      }
      #pragma unroll
      for (int i = 0; i < 4; i++)
        #pragma unroll
        for (int j = 0; j < 4; j++)
          acc[i][j] = __builtin_amdgcn_mfma_f32_16x16x32_bf16(a[i], b[j], acc[i][j], 0, 0, 0);
    }
    __syncthreads();
  }

  // epilogue: bias (+RoPE for Q/K) + bf16 + scatter into [B,H,S,D]
  const int which = n0 >> 11;   // 0=q 1=k 2=v, uniform per block
  unsigned short* dst = (which == 0) ? Qo : (which == 1) ? Ko : Vo;
  float bv[4];
  #pragma unroll
  for (int j = 0; j < 4; j++) bv[j] = bias[n0 + wn + j*16 + lm];

  if (which < 2) {
    // RoPE pairs (d, d+32) = (acc[i][j], acc[i][j+2]) for j=0,1 (d = j*16+lm)
    #pragma unroll
    for (int j = 0; j < 2; j++) {
      const int n = n0 + wn + j*16 + lm;
      const int e = n & (EMB - 1), h = e >> 6, d = e & 63;   // d = j*16+lm < 32
      const float invf = EXP2F((float)d * -0.4152410118609203f);  // 10000^(-d/32)
      #pragma unroll
      for (int i = 0; i < 4; i++) {
        #pragma unroll
        for (int r = 0; r < 4; r++) {
          const int m = m0 + wm + i*16 + lq*4 + r;
          const int s = m >> 1, b = m & 1;
          const float v1 = acc[i][j][r]   + bv[j];
          const float v2 = acc[i][j+2][r] + bv[j+2];
          float sn, cs;
          __sincosf((float)s * invf, &sn, &cs);
          const size_t base = (((size_t)b * NH + h) * S_LEN + s) * HD + d;
          dst[base]      = f2bf(v1 * cs - v2 * sn);
          dst[base + 32] = f2bf(v2 * cs + v1 * sn);
        }
      }
    }
  } else {
    #pragma unroll
    for (int j = 0; j < 4; j++) {
      const int n = n0 + wn + j*16 + lm;
      const int e = n & (EMB - 1), h = e >> 6, d = e & 63;
      #pragma unroll
      for (int i = 0; i < 4; i++) {
        #pragma unroll
        for (int r = 0; r < 4; r++) {
          const int m = m0 + wm + i*16 + lq*4 + r;
          const int s = m >> 1, b = m & 1;
          dst[(((size_t)b * NH + h) * S_LEN + s) * HD + d] = f2bf(acc[i][j][r] + bv[j]);
        }
      }
    }
  }
}

// ---------------- V [B,H,S,D] -> VT [B,H,D,S] ----------------

__global__ __launch_bounds__(256) void transpose_v(
    const unsigned short* __restrict__ V, unsigned short* __restrict__ VT) {
  __shared__ unsigned short t[64][65];
  const int bh = blockIdx.y;
  const int s0 = blockIdx.x * 64;
  const int tx = threadIdx.x & 63, ty = threadIdx.x >> 6;  // ty 0..3
  const unsigned short* src = V + ((size_t)bh * S_LEN + s0) * HD;
  #pragma unroll
  for (int r = ty; r < 64; r += 4)
    t[r][tx] = src[(size_t)r * HD + tx];
  __syncthreads();
  unsigned short* dst = VT + (size_t)bh * HD * S_LEN + s0;
  #pragma unroll
  for (int r = ty; r < 64; r += 4)
    dst[(size_t)r * S_LEN + tx] = t[tx][r];
}

// ---------------- Flash attention (causal), bf16 MFMA, fixed-max softmax ----------------
// Block = (head, strip pair p / 15-p); 4 waves x 32 rows per strip. ONE tile
// loop serves both strips: each K/V tile is staged once (was twice), into a
// DOUBLE-buffered LDS region with a SINGLE barrier per tile — stage(t+1) is
// issued before compute(t), so the vmcnt drain at the barrier sits behind
// ~1500 cyc of MFMA+exp instead of being exposed (barriers/block: 68 -> nt+1).

__global__ __launch_bounds__(256) void attn_kernel(
    const unsigned short* __restrict__ Q,
    const unsigned short* __restrict__ K,
    const unsigned short* __restrict__ VT,
    unsigned short* __restrict__ ctx) {
  const int bh = blockIdx.x;               // b*32+h
  const int p  = blockIdx.y;               // 0..7 strip pair
  const int tid = threadIdx.x;
  const int wave = tid >> 6, lane = tid & 63;
  const int lm = lane & 15, lq = lane >> 4;
  const int b = bh >> 5, h = bh & 31;
  const char* Qb8 = (const char*)(Q  + (size_t)bh * S_LEN * HD);
  const char* Kb8 = (const char*)(K  + (size_t)bh * S_LEN * HD);
  const char* Vb8 = (const char*)(VT + (size_t)bh * HD * S_LEN);

  __shared__ __align__(16) unsigned short Ks[2][2][64][32];  // [buf][half][row][32]
  __shared__ __align__(16) unsigned short Vs[2][2][64][32];
  __shared__ __align__(16) unsigned short Pbuf[4][32][72];
  unsigned short* Pw = &Pbuf[wave][0][0];

  const float C = 0.18033688011112042f;    // (1/8) * log2(e)
  const int q0A = p * 128, q0B = (15 - p) * 128;
  const int r0A = q0A + wave * 32, r0B = q0B + wave * 32;
  const int nt = (q0B >> 6) + 2;           // heavy strip's tile count

  // staging indices: thread -> (row, 16B chunk)
  const int srw = tid >> 2, sc16 = (tid & 3) * 16;

  // Q fragments for both strips (A-layout): rows r0+i*16+lm, k = ks*32+lq*8
  bf16x8 qf[2][2][2];                      // [strip][i][ks]
  #pragma unroll
  for (int s = 0; s < 2; s++) {
    const int rr = (s == 0) ? r0A : r0B;
    #pragma unroll
    for (int i = 0; i < 2; i++)
      #pragma unroll
      for (int ks = 0; ks < 2; ks++)
        qf[s][i][ks] = *reinterpret_cast<const bf16x8*>(
            Qb8 + (size_t)(rr + i*16 + lm) * 128 + ks*64 + lq*16);
  }

  f32x4 O[2][2][4] = {};
  float l[2][2][4] = {};

  // stage tile 0 into buf 0
  {
    char* kd = (char*)&Ks[0][0][0][0];
    char* vd = (char*)&Vs[0][0][0][0];
    async_copy16(Kb8 + (size_t)srw * 128      + sc16, kd        + tid*16);
    async_copy16(Kb8 + (size_t)srw * 128 + 64 + sc16, kd + 4096 + tid*16);
    async_copy16(Vb8 + (size_t)srw * 4096      + sc16, vd        + tid*16);
    async_copy16(Vb8 + (size_t)srw * 4096 + 64 + sc16, vd + 4096 + tid*16);
  }
  __syncthreads();

  for (int t = 0; t < nt; t++) {
    const int t0 = t * 64;
    const int buf = t & 1;

    // prefetch tile t+1 into the other buffer (drained by end-of-iter barrier)
    if (t + 1 < nt) {
      const int t1 = t0 + 64;
      char* kd = (char*)&Ks[buf ^ 1][0][0][0];
      char* vd = (char*)&Vs[buf ^ 1][0][0][0];
      async_copy16(Kb8 + (size_t)(t1 + srw) * 128      + sc16, kd        + tid*16);
      async_copy16(Kb8 + (size_t)(t1 + srw) * 128 + 64 + sc16, kd + 4096 + tid*16);
      async_copy16(Vb8 + (size_t)srw * 4096 + t1*2      + sc16, vd        + tid*16);
      async_copy16(Vb8 + (size_t)srw * 4096 + t1*2 + 64 + sc16, vd + 4096 + tid*16);
    }

    const char* KsB = (const char*)&Ks[buf][0][0][0];
    const char* VsB = (const char*)&Vs[buf][0][0][0];

    #pragma unroll
    for (int s = 0; s < 2; s++) {
      const int rr = (s == 0) ? r0A : r0B;
      if (t0 <= rr + 31) {
        const bool clean = (t0 + 63 <= rr);
        const int jmax  = clean ? 4 : ((rr == t0) ? 2 : 4);
        const int kslim = clean ? 2 : ((rr == t0) ? 1 : 2);
        const int srow_c = rr + lq * 4;

        // S = Q K^T from LDS halves
        f32x4 sc[2][4] = {};
        #pragma unroll
        for (int ks = 0; ks < 2; ks++) {
          bf16x8 kf[4];
          #pragma unroll
          for (int j = 0; j < 4; j++)
            if (j < jmax)
              kf[j] = *reinterpret_cast<const bf16x8*>(
                  KsB + ks*4096 + (j*16 + lm)*64 + lq*16);
          #pragma unroll
          for (int i = 0; i < 2; i++)
            #pragma unroll
            for (int j = 0; j < 4; j++)
              if (j < jmax)
                sc[i][j] = __builtin_amdgcn_mfma_f32_16x16x32_bf16(
                    qf[s][i][ks], kf[j], sc[i][j], 0, 0, 0);
        }

        // exp (fixed max), accumulate per-lane l, write P
        if (clean) {
          #pragma unroll
          for (int i = 0; i < 2; i++)
            #pragma unroll
            for (int j = 0; j < 4; j++)
              #pragma unroll
              for (int r = 0; r < 4; r++) {
                const float pe = EXP2F(sc[i][j][r] * C);
                l[s][i][r] += pe;
                Pw[(i*16 + lq*4 + r) * 72 + j*16 + lm] = f2bf(pe);
              }
        } else {
          #pragma unroll
          for (int i = 0; i < 2; i++)
            #pragma unroll
            for (int j = 0; j < 4; j++)
              if (j < jmax)
                #pragma unroll
                for (int r = 0; r < 4; r++) {
                  const int srow = srow_c + i*16 + r;
                  const int tcol = t0 + j*16 + lm;
                  const float pe = (tcol <= srow) ? EXP2F(sc[i][j][r] * C) : 0.0f;
                  l[s][i][r] += pe;
                  Pw[(i*16 + lq*4 + r) * 72 + j*16 + lm] = f2bf(pe);
                }
        }

        // O += P V
        #pragma unroll
        for (int ks = 0; ks < 2; ks++) {
          if (ks < kslim) {
            bf16x8 pf[2], vf[4];
            #pragma unroll
            for (int i = 0; i < 2; i++)
              pf[i] = *reinterpret_cast<const bf16x8*>(Pw + (i*16 + lm)*72 + ks*32 + lq*8);
            #pragma unroll
            for (int j = 0; j < 4; j++)
              vf[j] = *reinterpret_cast<const bf16x8*>(
                  VsB + ks*4096 + (j*16 + lm)*64 + lq*16);
            #pragma unroll
            for (int i = 0; i < 2; i++)
              #pragma unroll
              for (int j = 0; j < 4; j++)
                O[s][i][j] = __builtin_amdgcn_mfma_f32_16x16x32_bf16(
                    pf[i], vf[j], O[s][i][j], 0, 0, 0);
          }
        }
      }
    }
    __syncthreads();   // all compute(t) done; stage(t+1) drained (vmcnt 0)
  }

  // epilogue: reduce l across 16-lane column groups, scale, store ctx [S,B,E]
  #pragma unroll
  for (int s = 0; s < 2; s++) {
    const int rr = (s == 0) ? r0A : r0B;
    #pragma unroll
    for (int i = 0; i < 2; i++) {
      #pragma unroll
      for (int r = 0; r < 4; r++) {
        float sum = l[s][i][r];
        sum += __shfl_xor(sum, 1, 64);
        sum += __shfl_xor(sum, 2, 64);
        sum += __shfl_xor(sum, 4, 64);
        sum += __shfl_xor(sum, 8, 64);
        const float inv = 1.0f / sum;
        const int srow = rr + lq*4 + i*16 + r;
        #pragma unroll
        for (int j = 0; j < 4; j++) {
          const int d = j*16 + lm;
          ctx[((size_t)srow * BATCH + b) * EMB + h*HD + d] = f2bf(O[s][i][j][r] * inv);
        }
      }
    }
  }
}

// ---------------- Output GEMM: ctx[4096,2048]bf16 x outWt[2048,2048]bf16 + bias -> f32 ----------------
// Same BK=64 XOR-swizzled structure as gemm_qkv.

__global__ __launch_bounds__(256) void gemm_out(
    const unsigned short* __restrict__ A,
    const unsigned short* __restrict__ Wt,
    const float* __restrict__ bias,
    float* __restrict__ out) {
  __shared__ __align__(16) unsigned short As[128 * 64];
  __shared__ __align__(16) unsigned short Bs[128 * 64];
  const int tid = threadIdx.x;
  const int n0 = blockIdx.x * 128;
  const int m0 = blockIdx.y * 128;
  const int wave = tid >> 6, lane = tid & 63;
  const int wm = (wave >> 1) * 64, wn = (wave & 1) * 64;
  const int lm = lane & 15, lq = lane >> 4;
  const int K = 2048;

  const int srow = tid >> 3;
  const int gch  = (tid & 7) ^ (srow & 7);
  const unsigned short* Ab = A  + (size_t)(m0 + srow) * K + gch * 8;
  const unsigned short* Bb = Wt + (size_t)(n0 + srow) * K + gch * 8;

  f32x4 acc[4][4] = {};

  for (int k0 = 0; k0 < K; k0 += 64) {
    #pragma unroll
    for (int rep = 0; rep < 4; rep++) {
      async_copy16(Ab + (size_t)rep * 32 * K + k0, As + (size_t)(tid + 256 * rep) * 8);
      async_copy16(Bb + (size_t)rep * 32 * K + k0, Bs + (size_t)(tid + 256 * rep) * 8);
    }
    __syncthreads();
    #pragma unroll
    for (int ks = 0; ks < 2; ks++) {
      bf16x8 a[4], b[4];
      #pragma unroll
      for (int i = 0; i < 4; i++) {
        const int R = wm + i*16 + lm;
        a[i] = *reinterpret_cast<const bf16x8*>(
            As + (size_t)R * 64 + (((ks*4 + lq) ^ (R & 7)) * 8));
      }
      #pragma unroll
      for (int j = 0; j < 4; j++) {
        const int R = wn + j*16 + lm;
        b[j] = *reinterpret_cast<const bf16x8*>(
            Bs + (size_t)R * 64 + (((ks*4 + lq) ^ (R & 7)) * 8));
      }
      #pragma unroll
      for (int i = 0; i < 4; i++)
        #pragma unroll
        for (int j = 0; j < 4; j++)
          acc[i][j] = __builtin_amdgcn_mfma_f32_16x16x32_bf16(a[i], b[j], acc[i][j], 0, 0, 0);
    }
    __syncthreads();
  }

  #pragma unroll
  for (int j = 0; j < 4; j++) {
    const int n = n0 + wn + j*16 + lm;
    const float bv = bias[n];
    #pragma unroll
    for (int i = 0; i < 4; i++) {
      #pragma unroll
      for (int r = 0; r < 4; r++) {
        const int m = m0 + wm + i*16 + lq*4 + r;
        out[(size_t)m * EMB + n] = acc[i][j][r] + bv;
      }
    }
  }
}

// ---------------- host launcher ----------------

extern "C" void kernel_launch(void* const* d_in, const int* in_sizes, int n_in,
                              void* d_out, int out_size, void* d_ws, size_t ws_size,
                              hipStream_t stream) {
  const float* hidden = (const float*)d_in[0];
  const float* qkv_w  = (const float*)d_in[1];
  const float* qkv_b  = (const float*)d_in[2];
  const float* out_w  = (const float*)d_in[3];
  const float* out_b  = (const float*)d_in[4];
  float* out = (float*)d_out;

  unsigned short* ws = (unsigned short*)d_ws;
  unsigned short* hbf   = ws;                                  // 4096*2048
  unsigned short* qkvwT = hbf   + (size_t)M_ROWS * EMB;        // 6144*2048
  unsigned short* outwT = qkvwT + (size_t)QKV_N * EMB;         // 2048*2048
  unsigned short* Qb    = outwT + (size_t)EMB * EMB;           // 64*2048*64 each
  unsigned short* Kb    = Qb    + (size_t)64 * S_LEN * HD;
  unsigned short* Vb    = Kb    + (size_t)64 * S_LEN * HD;
  unsigned short* VTb   = Vb    + (size_t)64 * S_LEN * HD;
  unsigned short* ctx   = VTb   + (size_t)64 * S_LEN * HD;     // 4096*2048

  // 1. casts / transposes
  cast_to_bf16<<<(M_ROWS * EMB / 4) / 256, 256, 0, stream>>>(hidden, hbf, M_ROWS * EMB / 4);
  transpose_cast<<<dim3(QKV_N / 32, EMB / 32), 256, 0, stream>>>(qkv_w, qkvwT, EMB, QKV_N);
  transpose_cast<<<dim3(EMB / 32, EMB / 32), 256, 0, stream>>>(out_w, outwT, EMB, EMB);

  // 2. fused QKV projection + bias + RoPE + scatter
  gemm_qkv<<<dim3(QKV_N / 128, M_ROWS / 128), 256, 0, stream>>>(hbf, qkvwT, qkv_b, Qb, Kb, Vb);

  // 3. V transpose
  transpose_v<<<dim3(S_LEN / 64, 64), 256, 0, stream>>>(Vb, VTb);

  // 4. causal flash attention (merged strip pair, double-buffered K/V, 1 barrier/tile)
  attn_kernel<<<dim3(64, 8), 256, 0, stream>>>(Qb, Kb, VTb, ctx);

  // 5. output projection
  gemm_out<<<dim3(EMB / 128, M_ROWS / 128), 256, 0, stream>>>(ctx, outwT, out_b, out);
}